// Round 9
// baseline (246.452 us; speedup 1.0000x reference)
//
#include <hip/hip_runtime.h>
#include <hip/hip_fp16.h>
#include <math.h>

#define BB 16
#define NN 96
#define NE 256
#define FF (BB*NN)      // 1536
#define ATOM 128
#define EDIM 16
#define HID 128
#define LAT 128
#define RBFN 16
#define CUTOFF 5.0f
#define ZEMB 32
#define E_ATT 1024
#define M0I 64
#define M1I 32
#define M0O 32
#define M1O 16
#define NODE_DIM 160
#define OUT_DIM 80
#define INVD 48
#define WNUM 4608

// ---- K1 block layout ----
#define K1_TP 192                   // [0,192)    fused GEMM+TP (self-contained)
#define K1_EDGE_AT 192              // [192,448)  4 edges/block: features + k-MLP
#define K1_Q_AT 448                 // [448,960)  8 q-rows/block
#define K1_GATE_AT 960              // [960,976)
#define K1_PREP_AT 976              // [976]
#define K1_BLKS 977

typedef _Float16 half8_t __attribute__((ext_vector_type(8)));
typedef float float4v __attribute__((ext_vector_type(4)));

__device__ __forceinline__ float silu_f(float x) { return x / (1.0f + expf(-x)); }

// =======================================================================
// K1: TP(GEMM+contract, coop-staged B) + edge k-MLP + q-MLP + gates + prep
// =======================================================================
__global__ __launch_bounds__(256) void k1(
    const float* __restrict__ h, const float* __restrict__ h_full,
    const float* __restrict__ z_emb, const int* __restrict__ z,
    const int* __restrict__ absorber, const float* __restrict__ e_feat,
    const int* __restrict__ att_dst, const float* __restrict__ att_dist,
    const float* __restrict__ att_vec,
    const float* __restrict__ rw1, const float* __restrict__ rb1,
    const float* __restrict__ rw2, const float* __restrict__ rb2,
    const float* __restrict__ kw1, const float* __restrict__ kb1,
    const float* __restrict__ kw2, const float* __restrict__ kb2,
    const float* __restrict__ kw3, const float* __restrict__ kb3,
    const float* __restrict__ qw1, const float* __restrict__ qb1,
    const float* __restrict__ qw2, const float* __restrict__ qb2,
    const float* __restrict__ qw3, const float* __restrict__ qb3,
    const float* __restrict__ ew1, const float* __restrict__ eb1,
    const float* __restrict__ ew2, const float* __restrict__ eb2,
    float* __restrict__ kmatw, float* __restrict__ qmat,
    float* __restrict__ gexp, float* __restrict__ virr,
    int* __restrict__ inv)
{
    __shared__ __align__(16) char smemraw[38592];
    float* smem = (float*)smemraw;
    int blk = blockIdx.x;
    int t = threadIdx.x;

    if (blk < K1_TP) {
        // cls: 0 -> out0[:,0:16) (even SEG0/SEG3 tiles); 1 -> out0[:,16:32) (odd);
        // 2 -> out1 (SEG1+SEG2). tile -> edges [tile*16, tile*16+16).
        // LDS: cS [16][136]h @0 (aliases winf) | fbase floats @4352 | hS @17088 | Bs 4x[16][136]h @21184
        __half* cS    = (__half*)smemraw;               // [16][136] halves (MFMA out)
        float*  winf  = (float*)smemraw;                // [16][52] floats (dead before MFMA)
        float*  fbase = (float*)(smemraw + 4352);
        float* x0f  = fbase;                            // [16][64]
        float* x1f  = fbase + 1024;                     // [16][96]
        float* xyf  = fbase + 2560;                     // [16][32]
        float* y1f  = fbase + 3072;                     // [16][4]
        float* envf = fbase + 3136;                     // [16]
        float* dS   = fbase + 3152;                     // [16]
        int*   fI   = (int*)(fbase + 3168);             // [16]
        _Float16* hS = (_Float16*)(smemraw + 17088);    // [16][128] halves
        __half*   Bs = (__half*)(smemraw + 21184);      // [4][16][136] halves

        int cls  = blk % 3;
        int tile16 = blk / 3;
        int e0t = tile16 * 16;
        int clsAdd = (cls == 1) ? 1 : 0;
        if (t < 16) {
            int e = e0t + t;
            int f = att_dst[e];
            fI[t] = f;
            float d = att_dist[e];
            dS[t] = d;
            envf[t] = (d < CUTOFF) ? 0.5f*(cosf(3.14159265358979323846f*d/CUTOFF) + 1.0f) : 0.0f;
            float vx = att_vec[3*e], vy = att_vec[3*e+1], vz = att_vec[3*e+2];
            float nrm = sqrtf(vx*vx + vy*vy + vz*vz);
            float is = 1.0f / fmaxf(nrm, 1e-8f);
            const float s3 = 1.7320508075688772f;
            y1f[t*4]   = s3*vx*is;
            y1f[t*4+1] = s3*vy*is;
            y1f[t*4+2] = s3*vz*is;
        }
        __syncthreads();
        for (int u = t; u < 16*49; u += 256) {
            int e = u / 49, j = u - 49*(u/49);
            int f = fI[e];
            float v;
            if (j < ZEMB) v = z_emb[z[f]*ZEMB + j];
            else if (j == ZEMB) { int b = f / NN, nn = f - b*NN; v = (absorber[b] == nn) ? 1.0f : 0.0f; }
            else {
                int jr = j - 33;
                const float delta = CUTOFF / (RBFN - 1);
                float diff = dS[e] - jr*delta;
                v = expf(-diff*diff / (2.0f*delta*delta));
            }
            winf[e*52 + j] = v;
        }
        for (int p = 0; p < 10; p++) {
            int idx = t + 256*p;
            int edge = idx / 160, j = idx - 160*edge;
            float v = h_full[fI[edge]*NODE_DIM + j];
            if (j < M0I) x0f[edge*64 + j] = v;
            else         x1f[edge*96 + (j - M0I)] = v;
        }
        __syncthreads();
        for (int p = 0; p < 2; p++) {
            int idx = t + 256*p;
            int edge = idx >> 5, i = idx & 31;
            xyf[edge*32 + i] = x1f[edge*96 + 3*i]*y1f[edge*4]
                             + x1f[edge*96 + 3*i+1]*y1f[edge*4+1]
                             + x1f[edge*96 + 3*i+2]*y1f[edge*4+2];
        }
        // hidden = silu(w_in @ rw1 + rb1): fp16 into hS (proven loop)
        {
            int e = t >> 4;
            const float* wf = winf + e*52;
            #pragma unroll
            for (int p = 0; p < 4; p++) {
                int c2 = 2*((t & 15) + 16*p);
                float2 a0 = *(const float2*)&rb1[c2];
                float2 a1 = make_float2(0.f, 0.f);
                #pragma unroll 8
                for (int i = 0; i < 48; i += 2) {
                    float x0v = wf[i], x1v = wf[i + 1];
                    float2 w0 = *(const float2*)&rw1[i*HID + c2];
                    float2 w1 = *(const float2*)&rw1[(i+1)*HID + c2];
                    a0.x += x0v*w0.x; a0.y += x0v*w0.y;
                    a1.x += x1v*w1.x; a1.y += x1v*w1.y;
                }
                {
                    float x0v = wf[48];
                    float2 w0 = *(const float2*)&rw1[48*HID + c2];
                    a0.x += x0v*w0.x; a0.y += x0v*w0.y;
                }
                *(__half2*)&hS[e*128 + c2] =
                    __floats2half2_rn(silu_f(a0.x + a1.x), silu_f(a0.y + a1.y));
            }
        }
        // stage group 0 (writes Bs; independent of hS/winf)
        {
            int kk = (t >> 2) & 63;
            int n4 = t & 3;
            #pragma unroll
            for (int p = 0; p < 4; p++) {
                int j = 0*4 + p;
                int ntg = (cls == 2) ? (128 + j) : (2*j + clsAdd + ((j >= 64) ? 96 : 0));
                const float* src = rw2 + (2*kk)*WNUM + ntg*16 + n4*4;
                float4 va = *(const float4*)src;
                float4 vb = *(const float4*)(src + WNUM);
                __half* bp = Bs + p*2176 + (n4*4)*136 + 2*kk;
                *(__half2*)(bp)         = __floats2half2_rn(va.x, vb.x);
                *(__half2*)(bp + 136)   = __floats2half2_rn(va.y, vb.y);
                *(__half2*)(bp + 272)   = __floats2half2_rn(va.z, vb.z);
                *(__half2*)(bp + 408)   = __floats2half2_rn(va.w, vb.w);
            }
        }
        __syncthreads();   // hS + Bs(0) visible; winf dead -> cS free

        int wv = t >> 6;
        int lane = t & 63;
        int mrow = lane & 15, quad = lane >> 4;
        half8_t af[4];
        #pragma unroll
        for (int kc = 0; kc < 4; kc++)
            af[kc] = *(const half8_t*)&hS[mrow*128 + quad*8 + kc*32];

        int edge = t >> 4, o = t & 15;
        int kkS = (t >> 2) & 63;
        int n4S = t & 3;
        float t00 = 0.f, t11 = 0.f;
        float t01 = 0.f, tm0 = 0.f, tm1 = 0.f, tm2 = 0.f;

        for (int g = 0; g < 24; g++) {
            // ---- MFMA: wave wv owns tile wv of this group ----
            {
                int j = g*4 + wv;
                int ntg = (cls == 2) ? (128 + j) : (2*j + clsAdd + ((j >= 64) ? 96 : 0));
                float4v acc = {0.f, 0.f, 0.f, 0.f};
                #pragma unroll
                for (int kc = 0; kc < 4; kc++) {
                    half8_t bfr = *(const half8_t*)&((_Float16*)Bs)[wv*2176 + mrow*136 + kc*32 + quad*8];
                    acc = __builtin_amdgcn_mfma_f32_16x16x32_f16(af[kc], bfr, acc, 0, 0, 0);
                }
                float bias = rb2[ntg*16 + mrow];
                #pragma unroll
                for (int r = 0; r < 4; r++)
                    cS[(quad*4 + r)*136 + wv*16 + mrow] = __float2half(acc[r] + bias);
            }
            __syncthreads();
            // ---- stage next group (overlaps TP contract) ----
            if (g + 1 < 24) {
                #pragma unroll
                for (int p = 0; p < 4; p++) {
                    int j = (g+1)*4 + p;
                    int ntg = (cls == 2) ? (128 + j) : (2*j + clsAdd + ((j >= 64) ? 96 : 0));
                    const float* src = rw2 + (2*kkS)*WNUM + ntg*16 + n4S*4;
                    float4 va = *(const float4*)src;
                    float4 vb = *(const float4*)(src + WNUM);
                    __half* bp = Bs + p*2176 + (n4S*4)*136 + 2*kkS;
                    *(__half2*)(bp)       = __floats2half2_rn(va.x, vb.x);
                    *(__half2*)(bp + 136) = __floats2half2_rn(va.y, vb.y);
                    *(__half2*)(bp + 272) = __floats2half2_rn(va.z, vb.z);
                    *(__half2*)(bp + 408) = __floats2half2_rn(va.w, vb.w);
                }
            }
            // ---- TP contract group g (j ascending, proven order) ----
            {
                const __half* cRow = cS + edge*136 + o;
                if (cls < 2) {
                    if (g < 16) {
                        #pragma unroll
                        for (int nt = 0; nt < 4; nt++)
                            t00 += x0f[edge*64 + g*4 + nt]*__half2float(cRow[nt*16]);
                    } else {
                        #pragma unroll
                        for (int nt = 0; nt < 4; nt++)
                            t11 += xyf[edge*32 + (g*4 + nt - 64)]*__half2float(cRow[nt*16]);
                    }
                } else {
                    if (g < 16) {
                        #pragma unroll
                        for (int nt = 0; nt < 4; nt++)
                            t01 += x0f[edge*64 + g*4 + nt]*__half2float(cRow[nt*16]);
                    } else {
                        #pragma unroll
                        for (int nt = 0; nt < 4; nt++) {
                            int i = g*4 + nt - 64;
                            float C = __half2float(cRow[nt*16]);
                            tm0 += x1f[edge*96 + 3*i]*C;
                            tm1 += x1f[edge*96 + 3*i+1]*C;
                            tm2 += x1f[edge*96 + 3*i+2]*C;
                        }
                    }
                }
            }
            __syncthreads();
        }
        const float alpha = 0.10206207261596575f;  // 1/sqrt(96)
        const float ccf   = 0.5773502691896258f;   // 1/sqrt(3)
        int f = fI[edge];
        float env = envf[edge];
        if (cls < 2) {
            virr[f*OUT_DIM + cls*16 + o] = alpha*(t00 + ccf*t11)*env;
        } else {
            float y0 = y1f[edge*4], y1v = y1f[edge*4+1], y2 = y1f[edge*4+2];
            virr[f*OUT_DIM + M0O + 3*o]     = alpha*ccf*(t01*y0 + tm0)*env;
            virr[f*OUT_DIM + M0O + 3*o + 1] = alpha*ccf*(t01*y1v + tm1)*env;
            virr[f*OUT_DIM + M0O + 3*o + 2] = alpha*ccf*(t01*y2 + tm2)*env;
        }
    } else if (blk < K1_Q_AT) {
        // ---- edge features + k-MLP (proven verbatim) ----
        float (*sin1)[184] = (float(*)[184])smem;
        float (*l1S)[128]  = (float(*)[128])(smem + 736);
        float (*l2S)[128]  = (float(*)[128])(smem + 736 + 512);
        int w = t >> 6;
        int c = t & 63;
        int e = (blk - K1_EDGE_AT)*4 + w;
        int f = att_dst[e];
        int b = f / NN, nn = f - b*NN;
        float d = att_dist[e];
        {
            float2 hv = *(const float2*)&h[f*ATOM + 2*c];
            sin1[w][2*c] = hv.x; sin1[w][2*c + 1] = hv.y;
        }
        if (c < ZEMB) sin1[w][ATOM + c] = z_emb[z[f]*ZEMB + c];
        if (c >= 32 && c < 48) {
            int j = c - 32;
            const float delta = CUTOFF / (RBFN - 1);
            float diff = d - j*delta;
            sin1[w][ATOM + ZEMB + 1 + j] = expf(-diff*diff / (2.0f*delta*delta));
        }
        if (c == 48) sin1[w][ATOM + ZEMB] = (absorber[b] == nn) ? 1.0f : 0.0f;
        __syncthreads();
        int c2 = 2*c;
        {   // k layer 1: 177 -> 128
            float2 a0 = *(const float2*)&kb1[c2];
            float2 a1 = make_float2(0.f, 0.f);
            #pragma unroll 8
            for (int i = 0; i < 176; i += 2) {
                float x0v = sin1[w][i], x1v = sin1[w][i + 1];
                float2 w0 = *(const float2*)&kw1[i*HID + c2];
                float2 w1 = *(const float2*)&kw1[(i+1)*HID + c2];
                a0.x += x0v*w0.x; a0.y += x0v*w0.y;
                a1.x += x1v*w1.x; a1.y += x1v*w1.y;
            }
            {
                float x0v = sin1[w][176];
                float2 w0 = *(const float2*)&kw1[176*HID + c2];
                a0.x += x0v*w0.x; a0.y += x0v*w0.y;
            }
            l1S[w][c2] = silu_f(a0.x + a1.x); l1S[w][c2+1] = silu_f(a0.y + a1.y);
        }
        __syncthreads();
        {   // k layer 2
            float2 a0 = *(const float2*)&kb2[c2];
            float2 a1 = make_float2(0.f, 0.f);
            #pragma unroll 8
            for (int i = 0; i < HID; i += 2) {
                float x0v = l1S[w][i], x1v = l1S[w][i + 1];
                float2 w0 = *(const float2*)&kw2[i*HID + c2];
                float2 w1 = *(const float2*)&kw2[(i+1)*HID + c2];
                a0.x += x0v*w0.x; a0.y += x0v*w0.y;
                a1.x += x1v*w1.x; a1.y += x1v*w1.y;
            }
            l2S[w][c2] = silu_f(a0.x + a1.x); l2S[w][c2+1] = silu_f(a0.y + a1.y);
        }
        __syncthreads();
        {   // k layer 3 -> kmat
            float2 a0 = *(const float2*)&kb3[c2];
            float2 a1 = make_float2(0.f, 0.f);
            #pragma unroll 8
            for (int i = 0; i < HID; i += 2) {
                float x0v = l2S[w][i], x1v = l2S[w][i + 1];
                float2 w0 = *(const float2*)&kw3[i*HID + c2];
                float2 w1 = *(const float2*)&kw3[(i+1)*HID + c2];
                a0.x += x0v*w0.x; a0.y += x0v*w0.y;
                a1.x += x1v*w1.x; a1.y += x1v*w1.y;
            }
            float2 o; o.x = a0.x + a1.x; o.y = a0.y + a1.y;
            *(float2*)&kmatw[f*HID + c2] = o;
        }
    } else if (blk < K1_GATE_AT) {
        // ---- q-MLP (proven verbatim) ----
        float* hA          = smem;
        float (*ef)[16]    = (float(*)[16])(smem + 128);
        float (*part)[128] = (float(*)[128])(smem + 256);
        float* l1S         = smem + 1280;
        float* l2S         = smem + 2304;
        int idx = blk - K1_Q_AT;
        int r0 = idx * 8;
        int b  = r0 >> 8;
        int e8 = r0 & 255;
        if (t < 32) *(float4*)&hA[t*4] = *(const float4*)&h[(b*NN + absorber[b])*ATOM + t*4];
        if (t >= 128 && t < 256) { int e = (t - 128) >> 4, j = t & 15; ef[e][j] = e_feat[(e8 + e)*EDIM + j]; }
        __syncthreads();
        int r = t >> 5, c0 = (t & 31)*4;
        {
            float4 a0 = make_float4(0,0,0,0);
            int k0 = r*16;
            #pragma unroll
            for (int k = 0; k < 16; k++) {
                float hv = hA[k0 + k];
                float4 w0 = *(const float4*)&qw1[(k0 + k)*HID + c0];
                a0.x += hv*w0.x; a0.y += hv*w0.y; a0.z += hv*w0.z; a0.w += hv*w0.w;
            }
            *(float4*)&part[r][c0] = a0;
        }
        __syncthreads();
        {
            float4 s = *(const float4*)&qb1[c0];
            #pragma unroll
            for (int g = 0; g < 8; g++) {
                float4 pg = *(const float4*)&part[g][c0];
                s.x += pg.x; s.y += pg.y; s.z += pg.z; s.w += pg.w;
            }
            #pragma unroll
            for (int j = 0; j < 16; j++) {
                float a = ef[r][j];
                float4 w0 = *(const float4*)&qw1[(ATOM + j)*HID + c0];
                s.x += a*w0.x; s.y += a*w0.y; s.z += a*w0.z; s.w += a*w0.w;
            }
            l1S[r*128 + c0]   = silu_f(s.x); l1S[r*128 + c0+1] = silu_f(s.y);
            l1S[r*128 + c0+2] = silu_f(s.z); l1S[r*128 + c0+3] = silu_f(s.w);
        }
        __syncthreads();
        {
            float4 a0 = *(const float4*)&qb2[c0];
            float4 a1 = make_float4(0,0,0,0);
            #pragma unroll 8
            for (int i = 0; i < HID; i += 2) {
                float x0v = l1S[r*128 + i], x1v = l1S[r*128 + i+1];
                float4 w0 = *(const float4*)&qw2[i*HID + c0];
                float4 w1 = *(const float4*)&qw2[(i+1)*HID + c0];
                a0.x += x0v*w0.x; a0.y += x0v*w0.y; a0.z += x0v*w0.z; a0.w += x0v*w0.w;
                a1.x += x1v*w1.x; a1.y += x1v*w1.y; a1.z += x1v*w1.z; a1.w += x1v*w1.w;
            }
            l2S[r*128 + c0]   = silu_f(a0.x + a1.x); l2S[r*128 + c0+1] = silu_f(a0.y + a1.y);
            l2S[r*128 + c0+2] = silu_f(a0.z + a1.z); l2S[r*128 + c0+3] = silu_f(a0.w + a1.w);
        }
        __syncthreads();
        {
            float4 a0 = *(const float4*)&qb3[c0];
            float4 a1 = make_float4(0,0,0,0);
            #pragma unroll 8
            for (int i = 0; i < HID; i += 2) {
                float x0v = l2S[r*128 + i], x1v = l2S[r*128 + i+1];
                float4 w0 = *(const float4*)&qw3[i*HID + c0];
                float4 w1 = *(const float4*)&qw3[(i+1)*HID + c0];
                a0.x += x0v*w0.x; a0.y += x0v*w0.y; a0.z += x0v*w0.z; a0.w += x0v*w0.w;
                a1.x += x1v*w1.x; a1.y += x1v*w1.y; a1.z += x1v*w1.z; a1.w += x1v*w1.w;
            }
            float4 o;
            o.x = a0.x + a1.x; o.y = a0.y + a1.y; o.z = a0.z + a1.z; o.w = a0.w + a1.w;
            *(float4*)&qmat[(r0 + r)*LAT + c0] = o;
        }
    } else if (blk < K1_PREP_AT) {
        // ---- gates (proven verbatim) ----
        float (*ef)[16]   = (float(*)[16])smem;
        float (*l1g)[128] = (float(*)[128])(smem + 256);
        float (*gg)[48]   = (float(*)[48])(smem + 256 + 2048);
        int e0 = (blk - K1_GATE_AT) * 16;
        { int e = t >> 4, i = t & 15; ef[e][i] = e_feat[(e0 + e)*EDIM + i]; }
        __syncthreads();
        int r = t >> 4, c0 = (t & 15)*8;
        {
            float4 a0 = *(const float4*)&eb1[c0];
            float4 a1 = *(const float4*)&eb1[c0 + 4];
            #pragma unroll
            for (int i = 0; i < EDIM; i++) {
                float a = ef[r][i];
                float4 w0 = *(const float4*)&ew1[i*HID + c0];
                float4 w1 = *(const float4*)&ew1[i*HID + c0 + 4];
                a0.x += a*w0.x; a0.y += a*w0.y; a0.z += a*w0.z; a0.w += a*w0.w;
                a1.x += a*w1.x; a1.y += a*w1.y; a1.z += a*w1.z; a1.w += a*w1.w;
            }
            l1g[r][c0]   = silu_f(a0.x); l1g[r][c0+1] = silu_f(a0.y);
            l1g[r][c0+2] = silu_f(a0.z); l1g[r][c0+3] = silu_f(a0.w);
            l1g[r][c0+4] = silu_f(a1.x); l1g[r][c0+5] = silu_f(a1.y);
            l1g[r][c0+6] = silu_f(a1.z); l1g[r][c0+7] = silu_f(a1.w);
        }
        __syncthreads();
        for (int u = t; u < 16*48; u += 256) {
            int e = u / 48, j = u - 48*(u/48);
            float acc = eb2[j];
            #pragma unroll 4
            for (int i = 0; i < HID; i++) acc += l1g[e][i]*ew2[i*48 + j];
            gg[e][j] = acc;
        }
        __syncthreads();
        for (int u = t; u < 16*80; u += 256) {
            int e = u / 80, cc = u - 80*(u/80);
            gexp[(e0 + e)*OUT_DIM + cc] = (cc < M0O) ? gg[e][cc] : gg[e][M0O + (cc - M0O)/3];
        }
    } else {
        // ---- prep: inv init + scatter ----
        for (int p = 0; p < 6; p++) inv[t + 256*p] = -1;
        __syncthreads();
        for (int p = 0; p < 4; p++) { int e = t + 256*p; inv[att_dst[e]] = e; }
    }
}

// =======================================================================
// K2: in-block scores GEMM + softmax + PV + final MLP
// 4 e-rows per block (1024 blocks, row = one wave) for 2x TLP.
// =======================================================================
__global__ __launch_bounds__(256) void k_attf(
    const float* __restrict__ qmat, const float* __restrict__ kmat,
    const int* __restrict__ inv,
    const float* __restrict__ virr, const float* __restrict__ gexp,
    const float* __restrict__ ow1, const float* __restrict__ ob1,
    const float* __restrict__ ow2, const float* __restrict__ ob2,
    const float* __restrict__ ow3, const float* __restrict__ ob3,
    float* __restrict__ out)
{
    int u0 = blockIdx.x;
    int b  = u0 >> 6;           // 16
    int e0 = (u0 & 63) * 4;     // 64 chunks of 4 rows
    int t = threadIdx.x;
    __shared__ float smem[6816];
    float* aS  = smem;           // [4][100]
    float* gS  = smem + 400;     // [4][84]
    float* pvS = smem + 736;     // [4][2][84]
    float* ocS = smem + 1408;    // [4][84]
    float* mS  = smem + 1744;    // [96]
    float* inS = smem + 1840;    // [4][48]
    float* q4  = smem + 2032;    // [4][132]
    float* Kt  = smem + 2560;    // [32][133] (scores phase)
    float* l1S = smem + 2560;    // [4][128] alias (MLP phase)
    float* l2S = smem + 3072;    // [4][128]

    if (t < 80) {
        int el = t / 20, c4 = t - 20*(t/20);
        *(float4*)&gS[el*84 + c4*4] = *(const float4*)&gexp[(e0 + el)*OUT_DIM + c4*4];
    }
    if (t < NN) mS[t] = ((unsigned)inv[b*NN + t] < E_ATT) ? 1.0f : 0.0f;
    int row = t >> 6, ln = t & 63;
    *(float2*)&q4[row*132 + ln*2] = *(const float2*)&qmat[(b*NE + e0 + row)*LAT + ln*2];

    // ---- scores: row x 96 n; lane owns n_a = ln, n_b = 64+ln (ln<32) ----
    float sacc_a = 0.f, sacc_b = 0.f;
    #pragma unroll
    for (int nt = 0; nt < 3; nt++) {
        __syncthreads();
        for (int p = 0; p < 4; p++) {
            int idx = t + 256*p; int n = idx >> 5, i4 = idx & 31;
            *(float4*)&Kt[n*133 + i4*4] = *(const float4*)&kmat[(b*NN + nt*32 + n)*LAT + i4*4];
        }
        __syncthreads();
        if ((ln >> 5) == nt) {
            const float* kp = &Kt[(ln & 31)*133];
            const float* qp = &q4[row*132];
            float a0 = 0.f, a1 = 0.f;
            #pragma unroll 16
            for (int i = 0; i < LAT; i += 2) {
                a0 += qp[i]*kp[i];
                a1 += qp[i+1]*kp[i+1];
            }
            sacc_a = a0 + a1;
        }
        if (nt == 2 && ln < 32) {
            const float* kp = &Kt[ln*133];
            const float* qp = &q4[row*132];
            float a0 = 0.f, a1 = 0.f;
            #pragma unroll 16
            for (int i = 0; i < LAT; i += 2) {
                a0 += qp[i]*kp[i];
                a1 += qp[i+1]*kp[i+1];
            }
            sacc_b = a0 + a1;
        }
    }

    // ---- masked scores + softmax over full 64-lane row ----
    {
        const float scale = 0.04419417382415922f;  // (1/HEADS)*HD^-0.5
        float m_a = mS[ln];
        float m_b = (ln < 32) ? mS[64 + ln] : 0.f;
        float s_a = (m_a != 0.f) ? sacc_a*scale : -1e9f;
        float s_b = (m_b != 0.f) ? sacc_b*scale : -1e9f;
        float mx = fmaxf(s_a, s_b);
        #pragma unroll
        for (int off = 1; off < 64; off <<= 1) mx = fmaxf(mx, __shfl_xor(mx, off));
        float e_a = expf(s_a - mx), e_b = expf(s_b - mx);
        float sm = e_a + e_b;
        #pragma unroll
        for (int off = 1; off < 64; off <<= 1) sm += __shfl_xor(sm, off);
        float r = 1.0f / sm;
        float p_a = m_a*e_a*r, p_b = m_b*e_b*r;
        float ss = p_a + p_b;
        #pragma unroll
        for (int off = 1; off < 64; off <<= 1) ss += __shfl_xor(ss, off);
        float is = 1.0f / fmaxf(ss, 1e-8f);
        aS[row*100 + ln] = p_a*is;
        if (ln < 32) aS[row*100 + 64 + ln] = p_b*is;
    }
    __syncthreads();

    // ---- PV: 4 rows x 20 c4 x 2 n-halves ----
    if (t < 160) {
        int prow = t / 40, idx = t % 40;
        int half = idx / 20, c4 = idx % 20;
        const float* vp = virr + (long)b*NN*OUT_DIM + c4*4;
        float4 acc = make_float4(0,0,0,0);
        int n0 = half*48;
        #pragma unroll 8
        for (int n = n0; n < n0 + 48; n++) {
            float a = aS[prow*100 + n];
            float4 v = *(const float4*)&vp[n*OUT_DIM];
            acc.x += a*v.x; acc.y += a*v.y; acc.z += a*v.z; acc.w += a*v.w;
        }
        *(float4*)&pvS[prow*168 + half*84 + c4*4] = acc;
    }
    __syncthreads();
    if (t < 80) {
        int prow = t / 20, c4 = t % 20;
        float4 A = *(float4*)&pvS[prow*168 + c4*4];
        float4 Bv = *(float4*)&pvS[prow*168 + 84 + c4*4];
        float4 g = *(float4*)&gS[prow*84 + c4*4];
        float4 o;
        o.x = (A.x + Bv.x)*g.x; o.y = (A.y + Bv.y)*g.y;
        o.z = (A.z + Bv.z)*g.z; o.w = (A.w + Bv.w)*g.w;
        *(float4*)&ocS[prow*84 + c4*4] = o;
    }
    __syncthreads();

    if (t < 4*INVD) {
        int el = t / INVD, j = t - INVD*(t/INVD);
        float val;
        if (j < M0O) val = ocS[el*84 + j];
        else {
            int o = j - M0O;
            float x = ocS[el*84 + M0O + 3*o], y = ocS[el*84 + M0O + 3*o + 1], zz = ocS[el*84 + M0O + 3*o + 2];
            val = sqrtf(x*x + y*y + zz*zz + 1e-12f);
        }
        inS[el*INVD + j] = val;
    }
    __syncthreads();

    int r = t >> 6, cc = (t & 63)*2;
    {
        float2 a0 = *(const float2*)&ob1[cc];
        float2 a1 = make_float2(0.f, 0.f);
        #pragma unroll 8
        for (int i = 0; i < INVD; i += 2) {
            float x0v = inS[r*INVD + i], x1v = inS[r*INVD + i+1];
            float2 w0 = *(const float2*)&ow1[i*HID + cc];
            float2 w1 = *(const float2*)&ow1[(i+1)*HID + cc];
            a0.x += x0v*w0.x; a0.y += x0v*w0.y;
            a1.x += x1v*w1.x; a1.y += x1v*w1.y;
        }
        l1S[r*128 + cc]   = silu_f(a0.x + a1.x);
        l1S[r*128 + cc+1] = silu_f(a0.y + a1.y);
    }
    __syncthreads();
    {
        float2 a0 = *(const float2*)&ob2[cc];
        float2 a1 = make_float2(0.f, 0.f);
        #pragma unroll 8
        for (int i = 0; i < HID; i += 2) {
            float x0v = l1S[r*128 + i], x1v = l1S[r*128 + i+1];
            float2 w0 = *(const float2*)&ow2[i*HID + cc];
            float2 w1 = *(const float2*)&ow2[(i+1)*HID + cc];
            a0.x += x0v*w0.x; a0.y += x0v*w0.y;
            a1.x += x1v*w1.x; a1.y += x1v*w1.y;
        }
        l2S[r*128 + cc]   = silu_f(a0.x + a1.x);
        l2S[r*128 + cc+1] = silu_f(a0.y + a1.y);
    }
    __syncthreads();
    {
        float2 a0 = *(const float2*)&ob3[cc];
        float2 a1 = make_float2(0.f, 0.f);
        #pragma unroll 8
        for (int i = 0; i < HID; i += 2) {
            float x0v = l2S[r*128 + i], x1v = l2S[r*128 + i+1];
            float2 w0 = *(const float2*)&ow3[i*HID + cc];
            float2 w1 = *(const float2*)&ow3[(i+1)*HID + cc];
            a0.x += x0v*w0.x; a0.y += x0v*w0.y;
            a1.x += x1v*w1.x; a1.y += x1v*w1.y;
        }
        float2 o;
        o.x = a0.x + a1.x; o.y = a0.y + a1.y;
        *(float2*)&out[((b*NE + e0) + r)*LAT + cc] = o;
    }
}

extern "C" void kernel_launch(void* const* d_in, const int* in_sizes, int n_in,
                              void* d_out, int out_size, void* d_ws, size_t ws_size,
                              hipStream_t stream) {
    const float* h        = (const float*)d_in[0];
    const float* h_full   = (const float*)d_in[1];
    const float* e_feat   = (const float*)d_in[2];
    const float* att_dist = (const float*)d_in[3];
    const float* att_vec  = (const float*)d_in[4];
    const float* z_emb    = (const float*)d_in[5];
    const float* rw1 = (const float*)d_in[6];  const float* rb1 = (const float*)d_in[7];
    const float* rw2 = (const float*)d_in[8];  const float* rb2 = (const float*)d_in[9];
    const float* ew1 = (const float*)d_in[10]; const float* eb1 = (const float*)d_in[11];
    const float* ew2 = (const float*)d_in[12]; const float* eb2 = (const float*)d_in[13];
    const float* qw1 = (const float*)d_in[14]; const float* qb1 = (const float*)d_in[15];
    const float* qw2 = (const float*)d_in[16]; const float* qb2 = (const float*)d_in[17];
    const float* qw3 = (const float*)d_in[18]; const float* qb3 = (const float*)d_in[19];
    const float* kw1 = (const float*)d_in[20]; const float* kb1 = (const float*)d_in[21];
    const float* kw2 = (const float*)d_in[22]; const float* kb2 = (const float*)d_in[23];
    const float* kw3 = (const float*)d_in[24]; const float* kb3 = (const float*)d_in[25];
    const float* ow1 = (const float*)d_in[26]; const float* ob1 = (const float*)d_in[27];
    const float* ow2 = (const float*)d_in[28]; const float* ob2 = (const float*)d_in[29];
    const float* ow3 = (const float*)d_in[30]; const float* ob3 = (const float*)d_in[31];
    const int* z        = (const int*)d_in[32];
    const int* absorber = (const int*)d_in[34];
    const int* att_dst  = (const int*)d_in[35];

    float* ws = (float*)d_ws;
    int*   inv     = (int*)ws;                    // 1536
    float* kmat    = ws + 5632;                   // 196608 (1536x128)
    float* qmat    = ws + 202240;                 // 524288 (4096x128)
    float* gexp    = ws + 726528;                 // 20480
    float* virr    = ws + 747008;                 // 122880 (1536x80)

    float* out = (float*)d_out;

    k1<<<K1_BLKS, 256, 0, stream>>>(h, h_full, z_emb, z, absorber, e_feat,
                                    att_dst, att_dist, att_vec,
                                    rw1, rb1, rw2, rb2,
                                    kw1, kb1, kw2, kb2, kw3, kb3,
                                    qw1, qb1, qw2, qb2, qw3, qb3,
                                    ew1, eb1, ew2, eb2,
                                    kmat, qmat, gexp, virr, inv);
    k_attf<<<BB*64, 256, 0, stream>>>(qmat, kmat, inv, virr, gexp,
                                      ow1, ob1, ow2, ob2, ow3, ob3, out);
}

// Round 10
// 208.764 us; speedup vs baseline: 1.1805x; 1.1805x over previous
//
#include <hip/hip_runtime.h>
#include <hip/hip_fp16.h>
#include <math.h>

#define BB 16
#define NN 96
#define NE 256
#define FF (BB*NN)      // 1536
#define ATOM 128
#define EDIM 16
#define HID 128
#define LAT 128
#define RBFN 16
#define CUTOFF 5.0f
#define ZEMB 32
#define E_ATT 1024
#define M0I 64
#define M1I 32
#define M0O 32
#define M1O 16
#define NODE_DIM 160
#define OUT_DIM 80
#define INVD 48
#define WNUM 4608

// ---- K1 block layout ----
#define K1_TP 192                   // [0,192)    fused GEMM+TP (self-contained)
#define K1_EDGE_AT 192              // [192,448)  4 edges/block: features + k-MLP
#define K1_Q_AT 448                 // [448,960)  8 q-rows/block
#define K1_GATE_AT 960              // [960,976)
#define K1_PREP_AT 976              // [976]
#define K1_BLKS 977

typedef _Float16 half8_t __attribute__((ext_vector_type(8)));
typedef float float4v __attribute__((ext_vector_type(4)));

__device__ __forceinline__ float silu_f(float x) { return x / (1.0f + expf(-x)); }

// =======================================================================
// K1: TP(GEMM+contract) + edge k-MLP + q-MLP + gates + prep  (R8-proven)
// =======================================================================
__global__ __launch_bounds__(256) void k1(
    const float* __restrict__ h, const float* __restrict__ h_full,
    const float* __restrict__ z_emb, const int* __restrict__ z,
    const int* __restrict__ absorber, const float* __restrict__ e_feat,
    const int* __restrict__ att_dst, const float* __restrict__ att_dist,
    const float* __restrict__ att_vec,
    const float* __restrict__ rw1, const float* __restrict__ rb1,
    const float* __restrict__ rw2, const float* __restrict__ rb2,
    const float* __restrict__ kw1, const float* __restrict__ kb1,
    const float* __restrict__ kw2, const float* __restrict__ kb2,
    const float* __restrict__ kw3, const float* __restrict__ kb3,
    const float* __restrict__ qw1, const float* __restrict__ qb1,
    const float* __restrict__ qw2, const float* __restrict__ qb2,
    const float* __restrict__ qw3, const float* __restrict__ qb3,
    const float* __restrict__ ew1, const float* __restrict__ eb1,
    const float* __restrict__ ew2, const float* __restrict__ eb2,
    float* __restrict__ kmatw, float* __restrict__ qmat,
    float* __restrict__ gexp, float* __restrict__ virr,
    int* __restrict__ inv)
{
    __shared__ __align__(16) char smemraw[21248];
    float* smem = (float*)smemraw;
    int blk = blockIdx.x;
    int t = threadIdx.x;

    if (blk < K1_TP) {
        // cls: 0 -> out0[:,0:16) (even SEG0/SEG3 tiles); 1 -> out0[:,16:32) (odd);
        // 2 -> out1 (SEG1+SEG2). tile -> edges [tile*16, tile*16+16).
        __half* cS   = (__half*)smemraw;                // [16][136] halves (MFMA phase)
        float*  winf = (float*)smemraw;                 // [16][52] floats (aliases cS; dead before MFMA)
        float*  fbase = (float*)smemraw + 1088;
        float* x0f  = fbase;                            // [16][64]
        float* x1f  = fbase + 1024;                     // [16][96]
        float* xyf  = fbase + 2560;                     // [16][32]
        float* y1f  = fbase + 3072;                     // [16][4]
        float* envf = fbase + 3136;                     // [16]
        float* dS   = fbase + 3152;                     // [16]
        int*   fI   = (int*)(fbase + 3168);             // [16]
        _Float16* hS = (_Float16*)(smemraw + 17088);    // [16][128] halves

        int cls  = blk % 3;
        int tile = blk / 3;
        int e0t = tile * 16;
        if (t < 16) {
            int e = e0t + t;
            int f = att_dst[e];
            fI[t] = f;
            float d = att_dist[e];
            dS[t] = d;
            envf[t] = (d < CUTOFF) ? 0.5f*(cosf(3.14159265358979323846f*d/CUTOFF) + 1.0f) : 0.0f;
            float vx = att_vec[3*e], vy = att_vec[3*e+1], vz = att_vec[3*e+2];
            float nrm = sqrtf(vx*vx + vy*vy + vz*vz);
            float is = 1.0f / fmaxf(nrm, 1e-8f);
            const float s3 = 1.7320508075688772f;
            y1f[t*4]   = s3*vx*is;
            y1f[t*4+1] = s3*vy*is;
            y1f[t*4+2] = s3*vz*is;
        }
        __syncthreads();
        for (int u = t; u < 16*49; u += 256) {
            int e = u / 49, j = u - 49*(u/49);
            int f = fI[e];
            float v;
            if (j < ZEMB) v = z_emb[z[f]*ZEMB + j];
            else if (j == ZEMB) { int b = f / NN, nn = f - b*NN; v = (absorber[b] == nn) ? 1.0f : 0.0f; }
            else {
                int jr = j - 33;
                const float delta = CUTOFF / (RBFN - 1);
                float diff = dS[e] - jr*delta;
                v = expf(-diff*diff / (2.0f*delta*delta));
            }
            winf[e*52 + j] = v;
        }
        for (int p = 0; p < 10; p++) {
            int idx = t + 256*p;
            int edge = idx / 160, j = idx - 160*edge;
            float v = h_full[fI[edge]*NODE_DIM + j];
            if (j < M0I) x0f[edge*64 + j] = v;
            else         x1f[edge*96 + (j - M0I)] = v;
        }
        __syncthreads();
        for (int p = 0; p < 2; p++) {
            int idx = t + 256*p;
            int edge = idx >> 5, i = idx & 31;
            xyf[edge*32 + i] = x1f[edge*96 + 3*i]*y1f[edge*4]
                             + x1f[edge*96 + 3*i+1]*y1f[edge*4+1]
                             + x1f[edge*96 + 3*i+2]*y1f[edge*4+2];
        }
        // hidden = silu(w_in @ rw1 + rb1): 16 edges x 128 cols, fp16 into hS
        {
            int e = t >> 4;
            const float* wf = winf + e*52;
            #pragma unroll
            for (int p = 0; p < 4; p++) {
                int c2 = 2*((t & 15) + 16*p);
                float2 a0 = *(const float2*)&rb1[c2];
                float2 a1 = make_float2(0.f, 0.f);
                #pragma unroll 8
                for (int i = 0; i < 48; i += 2) {
                    float x0v = wf[i], x1v = wf[i + 1];
                    float2 w0 = *(const float2*)&rw1[i*HID + c2];
                    float2 w1 = *(const float2*)&rw1[(i+1)*HID + c2];
                    a0.x += x0v*w0.x; a0.y += x0v*w0.y;
                    a1.x += x1v*w1.x; a1.y += x1v*w1.y;
                }
                {
                    float x0v = wf[48];
                    float2 w0 = *(const float2*)&rw1[48*HID + c2];
                    a0.x += x0v*w0.x; a0.y += x0v*w0.y;
                }
                *(__half2*)&hS[e*128 + c2] =
                    __floats2half2_rn(silu_f(a0.x + a1.x), silu_f(a0.y + a1.y));
            }
        }
        __syncthreads();   // winf now dead; cS region free for MFMA writes

        int wv = t >> 6;
        int lane = t & 63;
        int mrow = lane & 15, quad = lane >> 4;
        half8_t af[4];
        #pragma unroll
        for (int kc = 0; kc < 4; kc++)
            af[kc] = *(const half8_t*)&hS[mrow*128 + quad*8 + kc*32];

        int edge = t >> 4, o = t & 15;
        float t00 = 0.f, t11 = 0.f;
        float t01 = 0.f, tm0 = 0.f, tm1 = 0.f, tm2 = 0.f;
        int clsAdd = (cls == 1) ? 1 : 0;

        for (int g = 0; g < 12; g++) {
            // ---- MFMA phase: wave wv computes local tiles {2wv, 2wv+1} ----
            #pragma unroll
            for (int sub = 0; sub < 2; sub++) {
                int ntl = 2*wv + sub;          // local tile 0..7
                int j = g*8 + ntl;             // 0..95
                int ntg = (cls == 2) ? (128 + j)
                                     : (2*j + clsAdd + ((j >= 64) ? 96 : 0));
                const float* bcol = rw2 + ntg*16 + mrow;
                float4v acc = {0.f, 0.f, 0.f, 0.f};
                #pragma unroll
                for (int kc = 0; kc < 4; kc++) {
                    half8_t bfr;
                    #pragma unroll
                    for (int m = 0; m < 8; m++)
                        bfr[m] = (_Float16)bcol[(quad*8 + kc*32 + m)*WNUM];
                    acc = __builtin_amdgcn_mfma_f32_16x16x32_f16(af[kc], bfr, acc, 0, 0, 0);
                }
                float bias = rb2[ntg*16 + mrow];
                #pragma unroll
                for (int r = 0; r < 4; r++)
                    cS[(quad*4 + r)*136 + ntl*16 + mrow] = __float2half(acc[r] + bias);
            }
            __syncthreads();
            // ---- TP phase: thread owns (edge, o) ----
            const __half* cRow = cS + edge*136 + o;
            if (cls < 2) {
                if (g < 8) {
                    #pragma unroll
                    for (int nt = 0; nt < 8; nt++)
                        t00 += x0f[edge*64 + g*8 + nt]*__half2float(cRow[nt*16]);
                } else {
                    #pragma unroll
                    for (int nt = 0; nt < 8; nt++)
                        t11 += xyf[edge*32 + (g*8 + nt - 64)]*__half2float(cRow[nt*16]);
                }
            } else {
                if (g < 8) {
                    #pragma unroll
                    for (int nt = 0; nt < 8; nt++)
                        t01 += x0f[edge*64 + g*8 + nt]*__half2float(cRow[nt*16]);
                } else {
                    #pragma unroll
                    for (int nt = 0; nt < 8; nt++) {
                        int i = g*8 + nt - 64;
                        float C = __half2float(cRow[nt*16]);
                        tm0 += x1f[edge*96 + 3*i]*C;
                        tm1 += x1f[edge*96 + 3*i+1]*C;
                        tm2 += x1f[edge*96 + 3*i+2]*C;
                    }
                }
            }
            __syncthreads();
        }
        const float alpha = 0.10206207261596575f;  // 1/sqrt(96)
        const float ccf   = 0.5773502691896258f;   // 1/sqrt(3)
        int f = fI[edge];
        float env = envf[edge];
        if (cls < 2) {
            virr[f*OUT_DIM + cls*16 + o] = alpha*(t00 + ccf*t11)*env;
        } else {
            float y0 = y1f[edge*4], y1v = y1f[edge*4+1], y2 = y1f[edge*4+2];
            virr[f*OUT_DIM + M0O + 3*o]     = alpha*ccf*(t01*y0 + tm0)*env;
            virr[f*OUT_DIM + M0O + 3*o + 1] = alpha*ccf*(t01*y1v + tm1)*env;
            virr[f*OUT_DIM + M0O + 3*o + 2] = alpha*ccf*(t01*y2 + tm2)*env;
        }
    } else if (blk < K1_Q_AT) {
        // ---- edge features + k-MLP (proven verbatim) ----
        float (*sin1)[184] = (float(*)[184])smem;
        float (*l1S)[128]  = (float(*)[128])(smem + 736);
        float (*l2S)[128]  = (float(*)[128])(smem + 736 + 512);
        int w = t >> 6;
        int c = t & 63;
        int e = (blk - K1_EDGE_AT)*4 + w;
        int f = att_dst[e];
        int b = f / NN, nn = f - b*NN;
        float d = att_dist[e];
        {
            float2 hv = *(const float2*)&h[f*ATOM + 2*c];
            sin1[w][2*c] = hv.x; sin1[w][2*c + 1] = hv.y;
        }
        if (c < ZEMB) sin1[w][ATOM + c] = z_emb[z[f]*ZEMB + c];
        if (c >= 32 && c < 48) {
            int j = c - 32;
            const float delta = CUTOFF / (RBFN - 1);
            float diff = d - j*delta;
            sin1[w][ATOM + ZEMB + 1 + j] = expf(-diff*diff / (2.0f*delta*delta));
        }
        if (c == 48) sin1[w][ATOM + ZEMB] = (absorber[b] == nn) ? 1.0f : 0.0f;
        __syncthreads();
        int c2 = 2*c;
        {   // k layer 1: 177 -> 128
            float2 a0 = *(const float2*)&kb1[c2];
            float2 a1 = make_float2(0.f, 0.f);
            #pragma unroll 8
            for (int i = 0; i < 176; i += 2) {
                float x0v = sin1[w][i], x1v = sin1[w][i + 1];
                float2 w0 = *(const float2*)&kw1[i*HID + c2];
                float2 w1 = *(const float2*)&kw1[(i+1)*HID + c2];
                a0.x += x0v*w0.x; a0.y += x0v*w0.y;
                a1.x += x1v*w1.x; a1.y += x1v*w1.y;
            }
            {
                float x0v = sin1[w][176];
                float2 w0 = *(const float2*)&kw1[176*HID + c2];
                a0.x += x0v*w0.x; a0.y += x0v*w0.y;
            }
            l1S[w][c2] = silu_f(a0.x + a1.x); l1S[w][c2+1] = silu_f(a0.y + a1.y);
        }
        __syncthreads();
        {   // k layer 2
            float2 a0 = *(const float2*)&kb2[c2];
            float2 a1 = make_float2(0.f, 0.f);
            #pragma unroll 8
            for (int i = 0; i < HID; i += 2) {
                float x0v = l1S[w][i], x1v = l1S[w][i + 1];
                float2 w0 = *(const float2*)&kw2[i*HID + c2];
                float2 w1 = *(const float2*)&kw2[(i+1)*HID + c2];
                a0.x += x0v*w0.x; a0.y += x0v*w0.y;
                a1.x += x1v*w1.x; a1.y += x1v*w1.y;
            }
            l2S[w][c2] = silu_f(a0.x + a1.x); l2S[w][c2+1] = silu_f(a0.y + a1.y);
        }
        __syncthreads();
        {   // k layer 3 -> kmat
            float2 a0 = *(const float2*)&kb3[c2];
            float2 a1 = make_float2(0.f, 0.f);
            #pragma unroll 8
            for (int i = 0; i < HID; i += 2) {
                float x0v = l2S[w][i], x1v = l2S[w][i + 1];
                float2 w0 = *(const float2*)&kw3[i*HID + c2];
                float2 w1 = *(const float2*)&kw3[(i+1)*HID + c2];
                a0.x += x0v*w0.x; a0.y += x0v*w0.y;
                a1.x += x1v*w1.x; a1.y += x1v*w1.y;
            }
            float2 o; o.x = a0.x + a1.x; o.y = a0.y + a1.y;
            *(float2*)&kmatw[f*HID + c2] = o;
        }
    } else if (blk < K1_GATE_AT) {
        // ---- q-MLP (proven verbatim) ----
        float* hA          = smem;
        float (*ef)[16]    = (float(*)[16])(smem + 128);
        float (*part)[128] = (float(*)[128])(smem + 256);
        float* l1S         = smem + 1280;
        float* l2S         = smem + 2304;
        int idx = blk - K1_Q_AT;
        int r0 = idx * 8;
        int b  = r0 >> 8;
        int e8 = r0 & 255;
        if (t < 32) *(float4*)&hA[t*4] = *(const float4*)&h[(b*NN + absorber[b])*ATOM + t*4];
        if (t >= 128 && t < 256) { int e = (t - 128) >> 4, j = t & 15; ef[e][j] = e_feat[(e8 + e)*EDIM + j]; }
        __syncthreads();
        int r = t >> 5, c0 = (t & 31)*4;
        {
            float4 a0 = make_float4(0,0,0,0);
            int k0 = r*16;
            #pragma unroll
            for (int k = 0; k < 16; k++) {
                float hv = hA[k0 + k];
                float4 w0 = *(const float4*)&qw1[(k0 + k)*HID + c0];
                a0.x += hv*w0.x; a0.y += hv*w0.y; a0.z += hv*w0.z; a0.w += hv*w0.w;
            }
            *(float4*)&part[r][c0] = a0;
        }
        __syncthreads();
        {
            float4 s = *(const float4*)&qb1[c0];
            #pragma unroll
            for (int g = 0; g < 8; g++) {
                float4 pg = *(const float4*)&part[g][c0];
                s.x += pg.x; s.y += pg.y; s.z += pg.z; s.w += pg.w;
            }
            #pragma unroll
            for (int j = 0; j < 16; j++) {
                float a = ef[r][j];
                float4 w0 = *(const float4*)&qw1[(ATOM + j)*HID + c0];
                s.x += a*w0.x; s.y += a*w0.y; s.z += a*w0.z; s.w += a*w0.w;
            }
            l1S[r*128 + c0]   = silu_f(s.x); l1S[r*128 + c0+1] = silu_f(s.y);
            l1S[r*128 + c0+2] = silu_f(s.z); l1S[r*128 + c0+3] = silu_f(s.w);
        }
        __syncthreads();
        {
            float4 a0 = *(const float4*)&qb2[c0];
            float4 a1 = make_float4(0,0,0,0);
            #pragma unroll 8
            for (int i = 0; i < HID; i += 2) {
                float x0v = l1S[r*128 + i], x1v = l1S[r*128 + i+1];
                float4 w0 = *(const float4*)&qw2[i*HID + c0];
                float4 w1 = *(const float4*)&qw2[(i+1)*HID + c0];
                a0.x += x0v*w0.x; a0.y += x0v*w0.y; a0.z += x0v*w0.z; a0.w += x0v*w0.w;
                a1.x += x1v*w1.x; a1.y += x1v*w1.y; a1.z += x1v*w1.z; a1.w += x1v*w1.w;
            }
            l2S[r*128 + c0]   = silu_f(a0.x + a1.x); l2S[r*128 + c0+1] = silu_f(a0.y + a1.y);
            l2S[r*128 + c0+2] = silu_f(a0.z + a1.z); l2S[r*128 + c0+3] = silu_f(a0.w + a1.w);
        }
        __syncthreads();
        {
            float4 a0 = *(const float4*)&qb3[c0];
            float4 a1 = make_float4(0,0,0,0);
            #pragma unroll 8
            for (int i = 0; i < HID; i += 2) {
                float x0v = l2S[r*128 + i], x1v = l2S[r*128 + i+1];
                float4 w0 = *(const float4*)&qw3[i*HID + c0];
                float4 w1 = *(const float4*)&qw3[(i+1)*HID + c0];
                a0.x += x0v*w0.x; a0.y += x0v*w0.y; a0.z += x0v*w0.z; a0.w += x0v*w0.w;
                a1.x += x1v*w1.x; a1.y += x1v*w1.y; a1.z += x1v*w1.z; a1.w += x1v*w1.w;
            }
            float4 o;
            o.x = a0.x + a1.x; o.y = a0.y + a1.y; o.z = a0.z + a1.z; o.w = a0.w + a1.w;
            *(float4*)&qmat[(r0 + r)*LAT + c0] = o;
        }
    } else if (blk < K1_PREP_AT) {
        // ---- gates (proven verbatim) ----
        float (*ef)[16]   = (float(*)[16])smem;
        float (*l1g)[128] = (float(*)[128])(smem + 256);
        float (*gg)[48]   = (float(*)[48])(smem + 256 + 2048);
        int e0 = (blk - K1_GATE_AT) * 16;
        { int e = t >> 4, i = t & 15; ef[e][i] = e_feat[(e0 + e)*EDIM + i]; }
        __syncthreads();
        int r = t >> 4, c0 = (t & 15)*8;
        {
            float4 a0 = *(const float4*)&eb1[c0];
            float4 a1 = *(const float4*)&eb1[c0 + 4];
            #pragma unroll
            for (int i = 0; i < EDIM; i++) {
                float a = ef[r][i];
                float4 w0 = *(const float4*)&ew1[i*HID + c0];
                float4 w1 = *(const float4*)&ew1[i*HID + c0 + 4];
                a0.x += a*w0.x; a0.y += a*w0.y; a0.z += a*w0.z; a0.w += a*w0.w;
                a1.x += a*w1.x; a1.y += a*w1.y; a1.z += a*w1.z; a1.w += a*w1.w;
            }
            l1g[r][c0]   = silu_f(a0.x); l1g[r][c0+1] = silu_f(a0.y);
            l1g[r][c0+2] = silu_f(a0.z); l1g[r][c0+3] = silu_f(a0.w);
            l1g[r][c0+4] = silu_f(a1.x); l1g[r][c0+5] = silu_f(a1.y);
            l1g[r][c0+6] = silu_f(a1.z); l1g[r][c0+7] = silu_f(a1.w);
        }
        __syncthreads();
        for (int u = t; u < 16*48; u += 256) {
            int e = u / 48, j = u - 48*(u/48);
            float acc = eb2[j];
            #pragma unroll 4
            for (int i = 0; i < HID; i++) acc += l1g[e][i]*ew2[i*48 + j];
            gg[e][j] = acc;
        }
        __syncthreads();
        for (int u = t; u < 16*80; u += 256) {
            int e = u / 80, cc = u - 80*(u/80);
            gexp[(e0 + e)*OUT_DIM + cc] = (cc < M0O) ? gg[e][cc] : gg[e][M0O + (cc - M0O)/3];
        }
    } else {
        // ---- prep: inv init + scatter ----
        for (int p = 0; p < 6; p++) inv[t + 256*p] = -1;
        __syncthreads();
        for (int p = 0; p < 4; p++) { int e = t + 256*p; inv[att_dst[e]] = e; }
    }
}

// =======================================================================
// K2: in-block scores GEMM + softmax + PV + final MLP (R8 structure,
// single-pass K staging: all 96 rows once, 2 barriers instead of 6)
// =======================================================================
__global__ __launch_bounds__(256) void k_attf(
    const float* __restrict__ qmat, const float* __restrict__ kmat,
    const int* __restrict__ inv,
    const float* __restrict__ virr, const float* __restrict__ gexp,
    const float* __restrict__ ow1, const float* __restrict__ ob1,
    const float* __restrict__ ow2, const float* __restrict__ ob2,
    const float* __restrict__ ow3, const float* __restrict__ ob3,
    float* __restrict__ out)
{
    int b  = blockIdx.x >> 5;
    int e0 = (blockIdx.x & 31) * 8;
    int t = threadIdx.x;
    __shared__ float smem[16448];
    float (*aS)[100]   = (float(*)[100])smem;            // 800
    float (*gS)[84]    = (float(*)[84])(smem + 800);     // 672
    float (*ocS)[84]   = (float(*)[84])(smem + 1472);    // 672
    float* mS          = smem + 2144;                    // 96
    float (*inS)[INVD] = (float(*)[INVD])(smem + 2240);  // 384
    float (*q8)[132]   = (float(*)[132])(smem + 2624);   // 1056 -> 3680
    float* Kt          = smem + 3680;                    // [96][133]=12768 (scores phase)
    float (*l1S)[HID]  = (float(*)[HID])(smem + 3680);   // alias (MLP phase)
    float (*l2S)[HID]  = (float(*)[HID])(smem + 3680 + 1024);

    if (t < 160) {
        int el = t / 20, c4 = t - 20*(t/20);
        *(float4*)&gS[el][c4*4] = *(const float4*)&gexp[(e0 + el)*OUT_DIM + c4*4];
    }
    if (t < NN) mS[t] = ((unsigned)inv[b*NN + t] < E_ATT) ? 1.0f : 0.0f;
    {
        int el = t >> 5, i4 = t & 31;
        *(float4*)&q8[el][i4*4] = *(const float4*)&qmat[(b*NE + e0 + el)*LAT + i4*4];
    }
    // ---- stage ALL 96 K rows once (stride 133 conflict-free) ----
    for (int p = 0; p < 12; p++) {
        int idx = t + 256*p; int n = idx >> 5, i4 = idx & 31;
        *(float4*)&Kt[n*133 + i4*4] = *(const float4*)&kmat[(b*NN + n)*LAT + i4*4];
    }
    __syncthreads();

    // ---- scores: 8 e-rows x 96 n; 3 back-to-back 128-dots per lane ----
    int el = t >> 5, tn = t & 31;
    float sacc0, sacc1, sacc2;
    {
        const float* qp = &q8[el][0];
        const float* kp0 = &Kt[tn*133];
        const float* kp1 = &Kt[(32 + tn)*133];
        const float* kp2 = &Kt[(64 + tn)*133];
        float a00 = 0.f, a01 = 0.f, a10 = 0.f, a11 = 0.f, a20 = 0.f, a21 = 0.f;
        #pragma unroll 16
        for (int i = 0; i < LAT; i += 2) {
            float q0 = qp[i], q1 = qp[i+1];
            a00 += q0*kp0[i]; a01 += q1*kp0[i+1];
            a10 += q0*kp1[i]; a11 += q1*kp1[i+1];
            a20 += q0*kp2[i]; a21 += q1*kp2[i+1];
        }
        sacc0 = a00 + a01; sacc1 = a10 + a11; sacc2 = a20 + a21;
    }

    // ---- masked scores + softmax (registers; same op order as proven) ----
    {
        const float scale = 0.04419417382415922f;  // (1/HEADS)*HD^-0.5
        int ng = tn;
        float m0 = mS[ng], m1 = mS[ng + 32], m2 = mS[ng + 64];
        float s0 = (m0 != 0.f) ? sacc0*scale : -1e9f;
        float s1 = (m1 != 0.f) ? sacc1*scale : -1e9f;
        float s2 = (m2 != 0.f) ? sacc2*scale : -1e9f;
        float mx = fmaxf(s0, fmaxf(s1, s2));
        #pragma unroll
        for (int off = 1; off < 32; off <<= 1) mx = fmaxf(mx, __shfl_xor(mx, off));
        float e0v = expf(s0 - mx), e1v = expf(s1 - mx), e2v = expf(s2 - mx);
        float sm = e0v + e1v + e2v;
        #pragma unroll
        for (int off = 1; off < 32; off <<= 1) sm += __shfl_xor(sm, off);
        float r = 1.0f / sm;
        float p0 = m0*e0v*r, p1 = m1*e1v*r, p2 = m2*e2v*r;
        float ss = p0 + p1 + p2;
        #pragma unroll
        for (int off = 1; off < 32; off <<= 1) ss += __shfl_xor(ss, off);
        float is = 1.0f / fmaxf(ss, 1e-8f);
        aS[el][ng]      = p0*is;
        aS[el][ng + 32] = p1*is;
        aS[el][ng + 64] = p2*is;
    }
    __syncthreads();

    if (t < 160) {
        int el2 = t / 20, c4 = t - 20*(t/20);
        const float* vp = virr + (long)b*NN*OUT_DIM + c4*4;
        float4 acc = make_float4(0,0,0,0);
        #pragma unroll 8
        for (int n = 0; n < NN; n++) {
            float a = aS[el2][n];
            float4 v = *(const float4*)&vp[n*OUT_DIM];
            acc.x += a*v.x; acc.y += a*v.y; acc.z += a*v.z; acc.w += a*v.w;
        }
        float4 g = *(float4*)&gS[el2][c4*4];
        float4 o; o.x = acc.x*g.x; o.y = acc.y*g.y; o.z = acc.z*g.z; o.w = acc.w*g.w;
        *(float4*)&ocS[el2][c4*4] = o;
    }
    __syncthreads();

    for (int u = t; u < 8*INVD; u += 256) {
        int el2 = u / INVD, j = u - INVD*(u/INVD);
        float val;
        if (j < M0O) val = ocS[el2][j];
        else {
            int o = j - M0O;
            float x = ocS[el2][M0O + 3*o], y = ocS[el2][M0O + 3*o + 1], zz = ocS[el2][M0O + 3*o + 2];
            val = sqrtf(x*x + y*y + zz*zz + 1e-12f);
        }
        inS[el2][j] = val;
    }
    __syncthreads();

    int r = t >> 5, c0 = (t & 31)*4;
    {
        float4 a0 = *(const float4*)&ob1[c0];
        float4 a1 = make_float4(0,0,0,0);
        #pragma unroll 8
        for (int i = 0; i < INVD; i += 2) {
            float x0v = inS[r][i], x1v = inS[r][i+1];
            float4 w0 = *(const float4*)&ow1[i*HID + c0];
            float4 w1 = *(const float4*)&ow1[(i+1)*HID + c0];
            a0.x += x0v*w0.x; a0.y += x0v*w0.y; a0.z += x0v*w0.z; a0.w += x0v*w0.w;
            a1.x += x1v*w1.x; a1.y += x1v*w1.y; a1.z += x1v*w1.z; a1.w += x1v*w1.w;
        }
        l1S[r][c0]   = silu_f(a0.x + a1.x); l1S[r][c0+1] = silu_f(a0.y + a1.y);
        l1S[r][c0+2] = silu_f(a0.z + a1.z); l1S[r][c0+3] = silu_f(a0.w + a1.w);
    }
    __syncthreads();
    {
        float4 a0 = *(const float4*)&ob2[c0];
        float4 a1 = make_float4(0,0,0,0);
        #pragma unroll 8
        for (int i = 0; i < HID; i += 2) {
            float x0v = l1S[r][i], x1v = l1S[r][i+1];
            float4 w0 = *(const float4*)&ow2[i*HID + c0];
            float4 w1 = *(const float4*)&ow2[(i+1)*HID + c0];
            a0.x += x0v*w0.x; a0.y += x0v*w0.y; a0.z += x0v*w0.z; a0.w += x0v*w0.w;
            a1.x += x1v*w1.x; a1.y += x1v*w1.y; a1.z += x1v*w1.z; a1.w += x1v*w1.w;
        }
        l2S[r][c0]   = silu_f(a0.x + a1.x); l2S[r][c0+1] = silu_f(a0.y + a1.y);
        l2S[r][c0+2] = silu_f(a0.z + a1.z); l2S[r][c0+3] = silu_f(a0.w + a1.w);
    }
    __syncthreads();
    {
        float4 a0 = *(const float4*)&ob3[c0];
        float4 a1 = make_float4(0,0,0,0);
        #pragma unroll 8
        for (int i = 0; i < HID; i += 2) {
            float x0v = l2S[r][i], x1v = l2S[r][i+1];
            float4 w0 = *(const float4*)&ow3[i*HID + c0];
            float4 w1 = *(const float4*)&ow3[(i+1)*HID + c0];
            a0.x += x0v*w0.x; a0.y += x0v*w0.y; a0.z += x0v*w0.z; a0.w += x0v*w0.w;
            a1.x += x1v*w1.x; a1.y += x1v*w1.y; a1.z += x1v*w1.z; a1.w += x1v*w1.w;
        }
        float4 o;
        o.x = a0.x + a1.x; o.y = a0.y + a1.y; o.z = a0.z + a1.z; o.w = a0.w + a1.w;
        *(float4*)&out[((b*NE + e0) + r)*LAT + c0] = o;
    }
}

extern "C" void kernel_launch(void* const* d_in, const int* in_sizes, int n_in,
                              void* d_out, int out_size, void* d_ws, size_t ws_size,
                              hipStream_t stream) {
    const float* h        = (const float*)d_in[0];
    const float* h_full   = (const float*)d_in[1];
    const float* e_feat   = (const float*)d_in[2];
    const float* att_dist = (const float*)d_in[3];
    const float* att_vec  = (const float*)d_in[4];
    const float* z_emb    = (const float*)d_in[5];
    const float* rw1 = (const float*)d_in[6];  const float* rb1 = (const float*)d_in[7];
    const float* rw2 = (const float*)d_in[8];  const float* rb2 = (const float*)d_in[9];
    const float* ew1 = (const float*)d_in[10]; const float* eb1 = (const float*)d_in[11];
    const float* ew2 = (const float*)d_in[12]; const float* eb2 = (const float*)d_in[13];
    const float* qw1 = (const float*)d_in[14]; const float* qb1 = (const float*)d_in[15];
    const float* qw2 = (const float*)d_in[16]; const float* qb2 = (const float*)d_in[17];
    const float* qw3 = (const float*)d_in[18]; const float* qb3 = (const float*)d_in[19];
    const float* kw1 = (const float*)d_in[20]; const float* kb1 = (const float*)d_in[21];
    const float* kw2 = (const float*)d_in[22]; const float* kb2 = (const float*)d_in[23];
    const float* kw3 = (const float*)d_in[24]; const float* kb3 = (const float*)d_in[25];
    const float* ow1 = (const float*)d_in[26]; const float* ob1 = (const float*)d_in[27];
    const float* ow2 = (const float*)d_in[28]; const float* ob2 = (const float*)d_in[29];
    const float* ow3 = (const float*)d_in[30]; const float* ob3 = (const float*)d_in[31];
    const int* z        = (const int*)d_in[32];
    const int* absorber = (const int*)d_in[34];
    const int* att_dst  = (const int*)d_in[35];

    float* ws = (float*)d_ws;
    int*   inv     = (int*)ws;                    // 1536
    float* kmat    = ws + 5632;                   // 196608 (1536x128)
    float* qmat    = ws + 202240;                 // 524288 (4096x128)
    float* gexp    = ws + 726528;                 // 20480
    float* virr    = ws + 747008;                 // 122880 (1536x80)

    float* out = (float*)d_out;

    k1<<<K1_BLKS, 256, 0, stream>>>(h, h_full, z_emb, z, absorber, e_feat,
                                    att_dst, att_dist, att_vec,
                                    rw1, rb1, rw2, rb2,
                                    kw1, kb1, kw2, kb2, kw3, kb3,
                                    qw1, qb1, qw2, qb2, qw3, qb3,
                                    ew1, eb1, ew2, eb2,
                                    kmat, qmat, gexp, virr, inv);
    k_attf<<<BB*32, 256, 0, stream>>>(qmat, kmat, inv, virr, gexp,
                                      ow1, ob1, ow2, ob2, ow3, ob3, out);
}